// Round 5
// baseline (3030.830 us; speedup 1.0000x reference)
//
#include <hip/hip_runtime.h>
#include <hip/hip_bf16.h>
#include <cstdint>

#define BATCH   4096
#define IN_DIM  1024
#define OUT_DIM 1024
#define NEXP    16

typedef __bf16 bf16;
typedef __attribute__((ext_vector_type(8))) __bf16 bf16x8;
typedef __attribute__((ext_vector_type(4))) float  f32x4;

#define AS1 __attribute__((address_space(1)))
#define AS3 __attribute__((address_space(3)))

__device__ __forceinline__ void gld_lds16(const bf16* g, bf16* l) {
    __builtin_amdgcn_global_load_lds((const AS1 void*)g, (AS3 void*)l, 16, 0, 0);
}

// ---------------------------------------------------------------------------
// Fused pre-kernel, register transpose only (no LDS).
// Blocks 0..2047 (W): wt2 tiles of 32o x 64k = 4 KB, fragment-ordered for the
//   mfma_16x16x32 A-operand: elem ((kk*2+wm)*64 + lane)*8 + j holds
//   W[ne*1024+ks*64+kk*32+lq*8+j][oblk*32+wm*16+lr], lane = lq*16+lr.
//   Tile index = oblk*256 + ks*16 + ne. 64 threads/tile, 4 ne per block.
//   Thread (go,kq): loads 8 rows x f32x4 (o = go*4..+3), emits 4 bf16x8
//   contiguous (64 B).
// Blocks 2048..2303 (x): tile (bblk*16+ks) = 256b x 64k = 32 KB, XOR-swizzled
//   row-major: stored chunk sc of row b holds logical chunk sc^(b&7).
// ---------------------------------------------------------------------------
__global__ void pre_convert(const float* __restrict__ x, const float* __restrict__ W,
                            bf16* __restrict__ xt, bf16* __restrict__ wt2) {
    int t = threadIdx.x;
    if (blockIdx.x < 2048) {
        int wb3 = blockIdx.x;
        int oblk = wb3 >> 6, ks = (wb3 >> 2) & 15, quad = wb3 & 3;
        int h = t >> 6, l = t & 63;
        int ne = quad * 4 + h;
        int go = l & 7, kq = l >> 3;           // o-group 0..7, k-chunk 0..7
        int kg = ne * 1024 + ks * 64 + kq * 8;
        int o  = oblk * 32 + go * 4;
        f32x4 ld[8];
#pragma unroll
        for (int j = 0; j < 8; j++)
            ld[j] = *(const f32x4*)(W + (size_t)(kg + j) * OUT_DIM + o);
        int kk = kq >> 2, lq = kq & 3, wm = go >> 2;
        size_t tileidx = (size_t)oblk * 256 + ks * 16 + ne;
        bf16* dst = wt2 + tileidx * 2048
                  + (size_t)(((kk * 2 + wm) * 64 + lq * 16 + (go & 3) * 4)) * 8;
#pragma unroll
        for (int i = 0; i < 4; i++) {
            bf16x8 v;
#pragma unroll
            for (int j = 0; j < 8; j++) v[j] = (bf16)ld[j][i];
            *(bf16x8*)(dst + i * 8) = v;
        }
    } else {
        int xb = blockIdx.x - 2048;            // bblk*16 + ks
        int bblk = xb >> 4, ks = xb & 15;
#pragma unroll
        for (int r = 0; r < 8; r++) {
            int q = r * 256 + t;               // 2048 chunks of 8 elems
            int b_loc = q >> 3, sc = q & 7;
            int ck = sc ^ (b_loc & 7);
            const float* src = x + (size_t)(bblk * 256 + b_loc) * IN_DIM + ks * 64 + ck * 8;
            f32x4 a = *(const f32x4*)src;
            f32x4 b = *(const f32x4*)(src + 4);
            bf16x8 v;
#pragma unroll
            for (int j = 0; j < 4; j++) { v[j] = (bf16)a[j]; v[4 + j] = (bf16)b[j]; }
            *(bf16x8*)(xt + (size_t)xb * 16384 + q * 8) = v;
        }
    }
}

// ---------------------------------------------------------------------------
// Transposed GEMM, mfma_16x16x32, f32x4 accs (no spill regime).
// Block 32o x 256b, 256 thr = 4 waves (wm 0..1 over o, wb 0..1 over b),
// wave tile 16o x 128b -> mt=1, bt=8, kk=2. Grid 16x32 = 512 = 2 blocks/CU.
// ks outer: x frags (64 VGPR) -> regs, reused over all 16 experts.
// Experts in pairs: W pair chunk (8 KB) double-buffered, staged one full
// region (~1240 cyc) ahead; ONE barrier per pair (128 total). Scales from
// global (L1-hot) into 32 VGPRs per 4-expert group. Fold in fp32 VALU
// (hides under MFMA, separate pipes).
// ---------------------------------------------------------------------------
__global__ __launch_bounds__(256, 2) void moe_gemm16t(
        const float* __restrict__ cw, const float* __restrict__ bias,
        const bf16* __restrict__ xt, const bf16* __restrict__ wt2,
        float* __restrict__ out) {
    int bblk = blockIdx.x;                 // 16
    int oblk = blockIdx.y;                 // 32
    int b0 = bblk * 256, o0 = oblk * 32;
    int t = threadIdx.x;
    int lane = t & 63, w = t >> 6;
    int wm = w & 1, wb = w >> 1;
    int lq = lane >> 4, lr = lane & 15;

    __shared__ bf16 Wb[2][4096];           // 2 x 8 KB two-expert chunks
    __shared__ bf16 Xb[16384];             // 32 KB x-tile

    const bf16* xsrc = xt + (size_t)(bblk * 16) * 16384;
    const bf16* wsrc = wt2 + (size_t)(oblk * 256) * 2048;
    const float* cwl = cw + (size_t)(b0 + wb * 128 + lr) * NEXP;

    // prologue: stage X(ks=0) + W pair 0
#pragma unroll
    for (int r = 0; r < 8; r++)
        gld_lds16(xsrc + r * 2048 + t * 8, &Xb[r * 2048 + t * 8]);
#pragma unroll
    for (int r = 0; r < 2; r++)
        gld_lds16(wsrc + r * 2048 + t * 8, &Wb[0][r * 2048 + t * 8]);

    const f32x4 fz = {0.f, 0.f, 0.f, 0.f};
    f32x4 acc[8];
#pragma unroll
    for (int bt = 0; bt < 8; bt++) acc[bt] = fz;

    for (int ks = 0; ks < 16; ks++) {
        const bf16* wks = wsrc + (size_t)ks * 16 * 2048;
        bf16x8 xf[8][2];
        f32x4 sc4[8];
#pragma unroll
        for (int p = 0; p < 8; p++) {      // expert pairs
            __syncthreads();               // chunk p staged; buf p^1 consumed
            if (p == 0) {                  // x frags -> regs (reused all ks)
#pragma unroll
                for (int bt = 0; bt < 8; bt++) {
                    int bl = wb * 128 + bt * 16 + lr;
#pragma unroll
                    for (int kk = 0; kk < 2; kk++)
                        xf[bt][kk] = *(const bf16x8*)
                            &Xb[bl * 64 + ((kk * 4 + lq) ^ (bl & 7)) * 8];
                }
            }
            // stage next W chunk into the other buffer
            if (p < 7) {
                const bf16* ns = wks + (size_t)(p + 1) * 4096 + t * 8;
#pragma unroll
                for (int r = 0; r < 2; r++)
                    gld_lds16(ns + r * 2048, &Wb[(p + 1) & 1][r * 2048 + t * 8]);
            } else if (ks < 15) {
                const bf16* ns = wsrc + (size_t)(ks + 1) * 16 * 2048 + t * 8;
#pragma unroll
                for (int r = 0; r < 2; r++)
                    gld_lds16(ns + r * 2048, &Wb[0][r * 2048 + t * 8]);
            }
            if (p == 1 && ks < 15) {       // all waves passed p=0 -> frags read
                const bf16* nx = xsrc + (size_t)(ks + 1) * 16384 + t * 8;
#pragma unroll
                for (int r = 0; r < 8; r++)
                    gld_lds16(nx + r * 2048, &Xb[r * 2048 + t * 8]);
            }
            if ((p & 1) == 0) {            // scales for 4-expert group
#pragma unroll
                for (int bt = 0; bt < 8; bt++)
                    sc4[bt] = *(const f32x4*)(cwl + bt * 16 * NEXP + (p >> 1) * 4);
            }
            const bf16* wbuf = &Wb[p & 1][0];
#pragma unroll
            for (int e = 0; e < 2; e++) {  // experts 2p, 2p+1
                bf16x8 wf0 = *(const bf16x8*)&wbuf[e * 2048 + (wm * 64 + lane) * 8];
                bf16x8 wf1 = *(const bf16x8*)&wbuf[e * 2048 + ((2 + wm) * 64 + lane) * 8];
#pragma unroll
                for (int bt = 0; bt < 8; bt++) {
                    f32x4 pp = __builtin_amdgcn_mfma_f32_16x16x32_bf16(
                        wf0, xf[bt][0], fz, 0, 0, 0);
                    pp = __builtin_amdgcn_mfma_f32_16x16x32_bf16(
                        wf1, xf[bt][1], pp, 0, 0, 0);
                    float s = sc4[bt][(p & 1) * 2 + e];
                    acc[bt] += s * pp;     // v_pk_fma_f32 x2
                }
            }
        }
    }

    // ---- bias as one MFMA k-step: A = bias^T frag, B = cw frag ----
    {
        bf16x8 bfrag;
        int o_l = o0 + wm * 16 + lr;
#pragma unroll
        for (int j = 0; j < 8; j++) bfrag[j] = (bf16)0.f;
        if (lq < 2) {
#pragma unroll
            for (int j = 0; j < 8; j++)
                bfrag[j] = (bf16)bias[(size_t)(lq * 8 + j) * OUT_DIM + o_l];
        }
#pragma unroll
        for (int bt = 0; bt < 8; bt++) {
            bf16x8 cf;
#pragma unroll
            for (int j = 0; j < 8; j++) cf[j] = (bf16)0.f;
            if (lq < 2) {
                const float* cr = cwl + bt * 16 * NEXP + lq * 8;
                f32x4 a = *(const f32x4*)cr;
                f32x4 b = *(const f32x4*)(cr + 4);
#pragma unroll
                for (int j = 0; j < 4; j++) { cf[j] = (bf16)a[j]; cf[4 + j] = (bf16)b[j]; }
            }
            acc[bt] = __builtin_amdgcn_mfma_f32_16x16x32_bf16(bfrag, cf, acc[bt], 0, 0, 0);
        }
    }

    // epilogue: relu + store. C/D: col = lane&15 (=b), row = lq*4 + r2 (=o)
#pragma unroll
    for (int bt = 0; bt < 8; bt++) {
        int b = b0 + wb * 128 + bt * 16 + lr;
        int o = o0 + wm * 16 + lq * 4;
        f32x4 v = acc[bt];
#pragma unroll
        for (int r2 = 0; r2 < 4; r2++) v[r2] = v[r2] > 0.f ? v[r2] : 0.f;
        *(f32x4*)(out + (size_t)b * OUT_DIM + o) = v;
    }
}

// ---------------------------------------------------------------------------
// Insurance fallback if ws_size is too small.
// ---------------------------------------------------------------------------
__global__ void fallback_kernel(const float* __restrict__ x, const float* __restrict__ cw,
                                const float* __restrict__ W, const float* __restrict__ bias,
                                float* __restrict__ out) {
    int o = blockIdx.x * 256 + threadIdx.x;
    int b = o >> 10, oc = o & 1023;
    const float* xr = x + (size_t)b * IN_DIM;
    float accv = 0.f;
    for (int n = 0; n < NEXP; n++) {
        const float* wr = W + (size_t)n * IN_DIM * OUT_DIM + oc;
        float z = 0.f;
        for (int i = 0; i < IN_DIM; i++) z += xr[i] * wr[(size_t)i * OUT_DIM];
        accv += cw[(size_t)b * NEXP + n] * (z + bias[n * OUT_DIM + oc]);
    }
    out[o] = accv > 0.f ? accv : 0.f;
}

extern "C" void kernel_launch(void* const* d_in, const int* in_sizes, int n_in,
                              void* d_out, int out_size, void* d_ws, size_t ws_size,
                              hipStream_t stream) {
    const float* x    = (const float*)d_in[0];
    const float* cw   = (const float*)d_in[1];
    const float* W    = (const float*)d_in[2];
    const float* bias = (const float*)d_in[3];
    float* out = (float*)d_out;

    const size_t wt_elems = (size_t)NEXP * IN_DIM * OUT_DIM;   // 16.7M bf16 = 32 MB
    const size_t xt_elems = (size_t)BATCH * IN_DIM;            // 4.2M bf16 = 8 MB
    if (ws_size < (wt_elems + xt_elems) * sizeof(bf16)) {
        fallback_kernel<<<(BATCH * OUT_DIM) / 256, 256, 0, stream>>>(x, cw, W, bias, out);
        return;
    }
    bf16* wt2 = (bf16*)d_ws;
    bf16* xt = wt2 + wt_elems;

    pre_convert<<<2304, 256, 0, stream>>>(x, W, xt, wt2);
    moe_gemm16t<<<dim3(16, 32), 256, 0, stream>>>(cw, bias, xt, wt2, out);
}

// Round 6
// 2024.929 us; speedup vs baseline: 1.4968x; 1.4968x over previous
//
#include <hip/hip_runtime.h>
#include <hip/hip_bf16.h>
#include <cstdint>

#define BATCH   4096
#define IN_DIM  1024
#define OUT_DIM 1024
#define NEXP    16

typedef __bf16 bf16;
typedef __attribute__((ext_vector_type(8))) __bf16 bf16x8;
typedef __attribute__((ext_vector_type(4))) float  f32x4;

#define AS1 __attribute__((address_space(1)))
#define AS3 __attribute__((address_space(3)))

__device__ __forceinline__ void gld_lds16(const bf16* g, bf16* l) {
    __builtin_amdgcn_global_load_lds((const AS1 void*)g, (AS3 void*)l, 16, 0, 0);
}

// ---------------------------------------------------------------------------
// Fused pre-kernel, register-transpose only (no LDS, no spill risk).
// Blocks 0..2047 (W): wt2 tiles of 64o x 64k = 8 KB, fragment-ordered for
//   mfma_16x16x32 A-operand. Tile idx = (oblk*16+ks)*16+ne. Chunk
//   c = (kk*4+og)*64 + lq*16 + lr holds W[ne*1024+ks*64+kk*32+lq*8+j]
//   [oblk*64+og*16+lr] at elem j. 128 thr/ne (2 ne per block):
//   thread (oq=t&15, kq=t>>4) loads 8 k-rows x f32x4 (256 B contiguous per
//   16 threads), emits 4 bf16x8 = 64 B contiguous.
// Blocks 2048..2559 (x): tile (bblk*16+ks) = 128b x 64k = 16 KB, XOR-swizzled
//   row-major: stored chunk sc of row b holds logical chunk sc^(b&7).
// ---------------------------------------------------------------------------
__global__ void pre_convert(const float* __restrict__ x, const float* __restrict__ W,
                            bf16* __restrict__ xt, bf16* __restrict__ wt2) {
    int t = threadIdx.x;
    if (blockIdx.x < 2048) {
        int wb3 = blockIdx.x;                  // (oblk<<7)|(ks<<3)|nepair
        int oblk = wb3 >> 7, ks = (wb3 >> 3) & 15, nepair = wb3 & 7;
        int h = t >> 7, t7 = t & 127;
        int ne = nepair * 2 + h;
        int oq = t7 & 15, kq = t7 >> 4;        // o-quad 0..15, k-oct 0..7
        int og = oq >> 2, l4 = oq & 3;
        int kg = ne * 1024 + ks * 64 + kq * 8;
        int o  = oblk * 64 + og * 16 + l4 * 4;
        f32x4 ld[8];
#pragma unroll
        for (int j = 0; j < 8; j++)
            ld[j] = *(const f32x4*)(W + (size_t)(kg + j) * OUT_DIM + o);
        int kk = kq >> 2, lq = kq & 3;
        size_t tileidx = (size_t)(oblk * 16 + ks) * 16 + ne;
        bf16* dst = wt2 + tileidx * 4096
                  + (size_t)((kk * 4 + og) * 64 + lq * 16 + l4 * 4) * 8;
#pragma unroll
        for (int i = 0; i < 4; i++) {
            bf16x8 v;
#pragma unroll
            for (int j = 0; j < 8; j++) v[j] = (bf16)ld[j][i];
            *(bf16x8*)(dst + i * 8) = v;
        }
    } else {
        int xb = blockIdx.x - 2048;            // bblk*16 + ks
        int bblk = xb >> 4, ks = xb & 15;
#pragma unroll
        for (int r = 0; r < 4; r++) {
            int q = r * 256 + t;               // 1024 chunks of 8 elems
            int b_loc = q >> 3, sc = q & 7;
            int ck = sc ^ (b_loc & 7);
            const float* src = x + (size_t)(bblk * 128 + b_loc) * IN_DIM + ks * 64 + ck * 8;
            f32x4 a = *(const f32x4*)src;
            f32x4 b = *(const f32x4*)(src + 4);
            bf16x8 v;
#pragma unroll
            for (int j = 0; j < 4; j++) { v[j] = (bf16)a[j]; v[4 + j] = (bf16)b[j]; }
            *(bf16x8*)(xt + (size_t)xb * 8192 + q * 8) = v;
        }
    }
}

// ---------------------------------------------------------------------------
// Transposed GEMM (R3 register regime + R2 LDS staging):
// D[o,b] = relu(Σ_ne cw[b,ne]·(W_ne^T x^T) + bias-term), out[b,o] = D.
// Block 64o x 128b, 256 thr = 4 waves (wm 0..1 o, wb 0..1 b), wave 32o x 64b.
// ks outer: x-tile dbuf (2x16 KB), x frags -> 32 VGPR, reused over 16 experts.
// ne inner: W tile (8 KB) dbuf via global_load_lds, ONE barrier per expert;
// prefetch issued ~600 cyc before its drain. Scales: per-lane f32x4 from
// global (L1-hot) per 4-expert group. Fold in fp32 VALU under MFMA.
// Live regs ~110: xf 32 + acc 32 + sc 16 + wf 16 + addr.
// ---------------------------------------------------------------------------
__global__ __launch_bounds__(256, 2) void moe_gemm_t2(
        const float* __restrict__ cw, const float* __restrict__ bias,
        const bf16* __restrict__ xt, const bf16* __restrict__ wt2,
        float* __restrict__ out) {
    int bblk = blockIdx.x;                 // 32
    int oblk = blockIdx.y;                 // 16
    int b0 = bblk * 128, o0 = oblk * 64;
    int t = threadIdx.x;
    int lane = t & 63, w = t >> 6;
    int wm = w & 1, wb = w >> 1;
    int lq = lane >> 4, lr = lane & 15;

    __shared__ bf16 Xb[2][8192];           // 2 x 16 KB x-tile dbuf
    __shared__ bf16 Wb[2][4096];           // 2 x 8 KB per-expert W dbuf

    const bf16* xsrc = xt + (size_t)(bblk * 16) * 8192;
    const bf16* wsrc = wt2 + (size_t)(oblk * 256) * 4096;   // tiles (ks*16+ne)
    const float* cwl = cw + (size_t)(b0 + wb * 64 + lr) * NEXP;

    // prologue: stage X(ks=0) + W tile 0
#pragma unroll
    for (int r = 0; r < 4; r++)
        gld_lds16(xsrc + r * 2048 + t * 8, &Xb[0][r * 2048 + t * 8]);
#pragma unroll
    for (int r = 0; r < 2; r++)
        gld_lds16(wsrc + r * 2048 + t * 8, &Wb[0][r * 2048 + t * 8]);

    const f32x4 fz = {0.f, 0.f, 0.f, 0.f};
    f32x4 acc[2][4];
#pragma unroll
    for (int mt = 0; mt < 2; mt++)
#pragma unroll
        for (int bt = 0; bt < 4; bt++) acc[mt][bt] = fz;

    for (int ks = 0; ks < 16; ks++) {
        bf16x8 xf[4][2];
        for (int g = 0; g < 4; g++) {      // 4-expert groups
            f32x4 sc[4];
#pragma unroll
            for (int bt = 0; bt < 4; bt++)
                sc[bt] = *(const f32x4*)(cwl + bt * 16 * NEXP + g * 4);
#pragma unroll
            for (int e = 0; e < 4; e++) {
                int ne = g * 4 + e;
                int tl = ks * 16 + ne;
                __syncthreads();           // Wb[tl&1] staged; prev buf consumed
                if (ne == 0) {             // x frags -> regs (reused all 16 ne)
#pragma unroll
                    for (int bt = 0; bt < 4; bt++) {
                        int bl = wb * 64 + bt * 16 + lr;
#pragma unroll
                        for (int kk = 0; kk < 2; kk++)
                            xf[bt][kk] = *(const bf16x8*)
                                &Xb[ks & 1][bl * 64 + ((kk * 4 + lq) ^ (bl & 7)) * 8];
                    }
                    if (ks < 15) {         // stage next x tile (other buffer)
                        const bf16* nx = xsrc + (size_t)(ks + 1) * 8192 + t * 8;
#pragma unroll
                        for (int r = 0; r < 4; r++)
                            gld_lds16(nx + r * 2048, &Xb[(ks + 1) & 1][r * 2048 + t * 8]);
                    }
                }
                if (tl < 255) {            // stage next W tile into other buffer
                    const bf16* nw = wsrc + (size_t)(tl + 1) * 4096 + t * 8;
#pragma unroll
                    for (int r = 0; r < 2; r++)
                        gld_lds16(nw + r * 2048, &Wb[(tl + 1) & 1][r * 2048 + t * 8]);
                }
                const bf16* wbuf = &Wb[tl & 1][0];
                bf16x8 wf[2][2];           // [kk][mt]
#pragma unroll
                for (int kk = 0; kk < 2; kk++)
#pragma unroll
                    for (int mt = 0; mt < 2; mt++)
                        wf[kk][mt] = *(const bf16x8*)
                            &wbuf[((kk * 4 + wm * 2 + mt) * 64 + lane) * 8];
#pragma unroll
                for (int mt = 0; mt < 2; mt++)
#pragma unroll
                    for (int bt = 0; bt < 4; bt++) {
                        f32x4 p = __builtin_amdgcn_mfma_f32_16x16x32_bf16(
                            wf[0][mt], xf[bt][0], fz, 0, 0, 0);
                        p = __builtin_amdgcn_mfma_f32_16x16x32_bf16(
                            wf[1][mt], xf[bt][1], p, 0, 0, 0);
                        float s = sc[bt][e];
                        acc[mt][bt] += s * p;          // v_pk_fma_f32 x2
                    }
            }
        }
    }

    // ---- bias as one MFMA k-step: A = bias^T frag, B = cw frag ----
    {
        bf16x8 bfrag[2];
#pragma unroll
        for (int mt = 0; mt < 2; mt++) {
            bf16x8 v;
#pragma unroll
            for (int j = 0; j < 8; j++) v[j] = (bf16)0.f;
            if (lq < 2) {                  // k = lq*8+j in 0..15 real
                int og = o0 + wm * 32 + mt * 16 + lr;
#pragma unroll
                for (int j = 0; j < 8; j++)
                    v[j] = (bf16)bias[(size_t)(lq * 8 + j) * OUT_DIM + og];
            }
            bfrag[mt] = v;
        }
#pragma unroll
        for (int bt = 0; bt < 4; bt++) {
            bf16x8 cf;
#pragma unroll
            for (int j = 0; j < 8; j++) cf[j] = (bf16)0.f;
            if (lq < 2) {
                const float* cr = cwl + bt * 16 * NEXP + lq * 8;
                f32x4 a = *(const f32x4*)cr;
                f32x4 b = *(const f32x4*)(cr + 4);
#pragma unroll
                for (int j = 0; j < 4; j++) { cf[j] = (bf16)a[j]; cf[4 + j] = (bf16)b[j]; }
            }
#pragma unroll
            for (int mt = 0; mt < 2; mt++)
                acc[mt][bt] = __builtin_amdgcn_mfma_f32_16x16x32_bf16(
                    bfrag[mt], cf, acc[mt][bt], 0, 0, 0);
        }
    }

    // epilogue: D[o,b] -> out[b,o]; lane f32x4 = 4 consecutive o at fixed b
#pragma unroll
    for (int mt = 0; mt < 2; mt++) {
        int og = o0 + wm * 32 + mt * 16 + lq * 4;
#pragma unroll
        for (int bt = 0; bt < 4; bt++) {
            int bg = b0 + wb * 64 + bt * 16 + lr;
            f32x4 v = acc[mt][bt];
#pragma unroll
            for (int r2 = 0; r2 < 4; r2++) v[r2] = v[r2] > 0.f ? v[r2] : 0.f;
            *(f32x4*)(out + (size_t)bg * OUT_DIM + og) = v;
        }
    }
}

// ---------------------------------------------------------------------------
// Insurance fallback if ws_size is too small.
// ---------------------------------------------------------------------------
__global__ void fallback_kernel(const float* __restrict__ x, const float* __restrict__ cw,
                                const float* __restrict__ W, const float* __restrict__ bias,
                                float* __restrict__ out) {
    int o = blockIdx.x * 256 + threadIdx.x;
    int b = o >> 10, oc = o & 1023;
    const float* xr = x + (size_t)b * IN_DIM;
    float accv = 0.f;
    for (int n = 0; n < NEXP; n++) {
        const float* wr = W + (size_t)n * IN_DIM * OUT_DIM + oc;
        float z = 0.f;
        for (int i = 0; i < IN_DIM; i++) z += xr[i] * wr[(size_t)i * OUT_DIM];
        accv += cw[(size_t)b * NEXP + n] * (z + bias[n * OUT_DIM + oc]);
    }
    out[o] = accv > 0.f ? accv : 0.f;
}

extern "C" void kernel_launch(void* const* d_in, const int* in_sizes, int n_in,
                              void* d_out, int out_size, void* d_ws, size_t ws_size,
                              hipStream_t stream) {
    const float* x    = (const float*)d_in[0];
    const float* cw   = (const float*)d_in[1];
    const float* W    = (const float*)d_in[2];
    const float* bias = (const float*)d_in[3];
    float* out = (float*)d_out;

    const size_t wt_elems = (size_t)NEXP * IN_DIM * OUT_DIM;   // 32 MB bf16
    const size_t xt_elems = (size_t)BATCH * IN_DIM;            // 8 MB bf16
    if (ws_size < (wt_elems + xt_elems) * sizeof(bf16)) {
        fallback_kernel<<<(BATCH * OUT_DIM) / 256, 256, 0, stream>>>(x, cw, W, bias, out);
        return;
    }
    bf16* wt2 = (bf16*)d_ws;
    bf16* xt = wt2 + wt_elems;

    pre_convert<<<2560, 256, 0, stream>>>(x, W, xt, wt2);
    moe_gemm_t2<<<dim3(32, 16), 256, 0, stream>>>(cw, bias, xt, wt2, out);
}

// Round 7
// 1895.880 us; speedup vs baseline: 1.5986x; 1.0681x over previous
//
#include <hip/hip_runtime.h>
#include <hip/hip_bf16.h>
#include <cstdint>

#define BATCH   4096
#define IN_DIM  1024
#define OUT_DIM 1024
#define NEXP    16

typedef __bf16 bf16;
typedef __attribute__((ext_vector_type(8))) __bf16 bf16x8;
typedef __attribute__((ext_vector_type(4))) float  f32x4;
typedef __attribute__((ext_vector_type(2))) float  f32x2;

#define AS1 __attribute__((address_space(1)))
#define AS3 __attribute__((address_space(3)))

__device__ __forceinline__ void gld_lds16(const bf16* g, bf16* l) {
    __builtin_amdgcn_global_load_lds((const AS1 void*)g, (AS3 void*)l, 16, 0, 0);
}

// ---------------------------------------------------------------------------
// Fused pre-kernel (verbatim from R6 — layouts correctness-proven).
// Blocks 0..2047 (W): wt2 tiles of 64o x 64k = 8 KB, fragment-ordered for
//   mfma_16x16x32 A-operand. Tile idx = (oblk*16+ks)*16+ne. Chunk
//   c = (kk*4+og)*64 + lq*16 + lr holds W[ne*1024+ks*64+kk*32+lq*8+j]
//   [oblk*64+og*16+lr] at elem j. Register transpose, no LDS.
// Blocks 2048..2559 (x): tile (bblk*16+ks) = 128b x 64k = 16 KB, XOR-swizzled
//   row-major: stored chunk sc of row b holds logical chunk sc^(b&7).
// ---------------------------------------------------------------------------
__global__ void pre_convert(const float* __restrict__ x, const float* __restrict__ W,
                            bf16* __restrict__ xt, bf16* __restrict__ wt2) {
    int t = threadIdx.x;
    if (blockIdx.x < 2048) {
        int wb3 = blockIdx.x;                  // (oblk<<7)|(ks<<3)|nepair
        int oblk = wb3 >> 7, ks = (wb3 >> 3) & 15, nepair = wb3 & 7;
        int h = t >> 7, t7 = t & 127;
        int ne = nepair * 2 + h;
        int oq = t7 & 15, kq = t7 >> 4;        // o-quad 0..15, k-oct 0..7
        int og = oq >> 2, l4 = oq & 3;
        int kg = ne * 1024 + ks * 64 + kq * 8;
        int o  = oblk * 64 + og * 16 + l4 * 4;
        f32x4 ld[8];
#pragma unroll
        for (int j = 0; j < 8; j++)
            ld[j] = *(const f32x4*)(W + (size_t)(kg + j) * OUT_DIM + o);
        int kk = kq >> 2, lq = kq & 3;
        size_t tileidx = (size_t)(oblk * 16 + ks) * 16 + ne;
        bf16* dst = wt2 + tileidx * 4096
                  + (size_t)((kk * 4 + og) * 64 + lq * 16 + l4 * 4) * 8;
#pragma unroll
        for (int i = 0; i < 4; i++) {
            bf16x8 v;
#pragma unroll
            for (int j = 0; j < 8; j++) v[j] = (bf16)ld[j][i];
            *(bf16x8*)(dst + i * 8) = v;
        }
    } else {
        int xb = blockIdx.x - 2048;            // bblk*16 + ks
        int bblk = xb >> 4, ks = xb & 15;
#pragma unroll
        for (int r = 0; r < 4; r++) {
            int q = r * 256 + t;               // 1024 chunks of 8 elems
            int b_loc = q >> 3, sc = q & 7;
            int ck = sc ^ (b_loc & 7);
            const float* src = x + (size_t)(bblk * 128 + b_loc) * IN_DIM + ks * 64 + ck * 8;
            f32x4 a = *(const f32x4*)src;
            f32x4 b = *(const f32x4*)(src + 4);
            bf16x8 v;
#pragma unroll
            for (int j = 0; j < 4; j++) { v[j] = (bf16)a[j]; v[4 + j] = (bf16)b[j]; }
            *(bf16x8*)(xt + (size_t)xb * 8192 + q * 8) = v;
        }
    }
}

// ---------------------------------------------------------------------------
// Transposed GEMM, spill-proofed (live regs ~110):
// D[o,b] = relu(Σ_ne cw[b,ne]·(W_ne^T x^T) + bias-term), out[b,o] = D.
// Block 64o x 128b, 4 waves (wm 0..1 o, wb 0..1 b), wave 32o x 64b.
// ks outer: single Xb buffer, x frags -> 32 VGPR reused over 16 experts;
// X(ks+1) staged during expert 1 (Xb dead after xf loads, proven by the
// expert-0 barrier). ne inner: manual unroll-2 pairs, Wb[0/1] per-expert
// dbuf via global_load_lds, ONE barrier per expert; prefetch issued at body
// top ~600 cyc before its drain. Scales: f32x2 per bt per pair from L1-hot
// cw (8 regs). Fold in fp32 VALU under MFMA (separate pipes, m114).
// ---------------------------------------------------------------------------
__global__ __launch_bounds__(256, 2) void moe_gemm_t3(
        const float* __restrict__ cw, const float* __restrict__ bias,
        const bf16* __restrict__ xt, const bf16* __restrict__ wt2,
        float* __restrict__ out) {
    int bblk = blockIdx.x;                 // 32
    int oblk = blockIdx.y;                 // 16
    int b0 = bblk * 128, o0 = oblk * 64;
    int t = threadIdx.x;
    int lane = t & 63, w = t >> 6;
    int wm = w & 1, wb = w >> 1;
    int lq = lane >> 4, lr = lane & 15;

    __shared__ bf16 Xb[8192];              // 16 KB x-tile (single buffer)
    __shared__ bf16 Wb[2][4096];           // 2 x 8 KB per-expert W dbuf

    const bf16* xsrc = xt + (size_t)(bblk * 16) * 8192;
    const bf16* wsrc = wt2 + (size_t)(oblk * 256) * 4096;   // tiles (ks*16+ne)
    const float* cwl = cw + (size_t)(b0 + wb * 64 + lr) * NEXP;

    // prologue: stage X(0) + W(0,0)
#pragma unroll
    for (int r = 0; r < 4; r++)
        gld_lds16(xsrc + r * 2048 + t * 8, &Xb[r * 2048 + t * 8]);
#pragma unroll
    for (int r = 0; r < 2; r++)
        gld_lds16(wsrc + r * 2048 + t * 8, &Wb[0][r * 2048 + t * 8]);

    const f32x4 fz = {0.f, 0.f, 0.f, 0.f};
    f32x4 acc[2][4];
#pragma unroll
    for (int mt = 0; mt < 2; mt++)
#pragma unroll
        for (int bt = 0; bt < 4; bt++) acc[mt][bt] = fz;

    for (int ks = 0; ks < 16; ks++) {
        __syncthreads();                   // X(ks) + W(ks,0) staged
        // x fragments -> registers (B-operand: n=b=lr, k=lq*8+j)
        bf16x8 xf[4][2];
#pragma unroll
        for (int bt = 0; bt < 4; bt++) {
            int bl = wb * 64 + bt * 16 + lr;
#pragma unroll
            for (int kk = 0; kk < 2; kk++)
                xf[bt][kk] = *(const bf16x8*)
                    &Xb[bl * 64 + ((kk * 4 + lq) ^ (bl & 7)) * 8];
        }
        const bf16* wks = wsrc + (size_t)ks * 16 * 4096;

        for (int np = 0; np < 8; np++) {
            // scales for this expert pair: f32x2 per bt (8 VGPRs, L1-hot)
            f32x2 sc2[4];
#pragma unroll
            for (int bt = 0; bt < 4; bt++)
                sc2[bt] = *(const f32x2*)(cwl + bt * 16 * NEXP + np * 2);

            // ---------- expert ne0 = 2np (buffer 0) ----------
            {
                // prefetch W(ks, 2np+1) -> Wb[1]
                const bf16* nw = wks + (size_t)(np * 2 + 1) * 4096 + t * 8;
#pragma unroll
                for (int r = 0; r < 2; r++)
                    gld_lds16(nw + r * 2048, &Wb[1][r * 2048 + t * 8]);
                bf16x8 wf[2][2];           // [kk][mt]
#pragma unroll
                for (int kk = 0; kk < 2; kk++)
#pragma unroll
                    for (int mt = 0; mt < 2; mt++)
                        wf[kk][mt] = *(const bf16x8*)
                            &Wb[0][((kk * 4 + wm * 2 + mt) * 64 + lane) * 8];
#pragma unroll
                for (int mt = 0; mt < 2; mt++)
#pragma unroll
                    for (int bt = 0; bt < 4; bt++) {
                        f32x4 p = __builtin_amdgcn_mfma_f32_16x16x32_bf16(
                            wf[0][mt], xf[bt][0], fz, 0, 0, 0);
                        p = __builtin_amdgcn_mfma_f32_16x16x32_bf16(
                            wf[1][mt], xf[bt][1], p, 0, 0, 0);
                        acc[mt][bt] += sc2[bt][0] * p;
                    }
                __syncthreads();           // Wb[1] staged; Wb[0] consumers done
            }
            // ---------- expert ne1 = 2np+1 (buffer 1) ----------
            {
                if (np < 7) {              // prefetch W(ks, 2np+2) -> Wb[0]
                    const bf16* nw = wks + (size_t)(np * 2 + 2) * 4096 + t * 8;
#pragma unroll
                    for (int r = 0; r < 2; r++)
                        gld_lds16(nw + r * 2048, &Wb[0][r * 2048 + t * 8]);
                } else if (ks < 15) {      // prefetch W(ks+1, 0) -> Wb[0]
                    const bf16* nw = wsrc + (size_t)(ks + 1) * 16 * 4096 + t * 8;
#pragma unroll
                    for (int r = 0; r < 2; r++)
                        gld_lds16(nw + r * 2048, &Wb[0][r * 2048 + t * 8]);
                }
                if (np == 0 && ks < 15) {  // stage X(ks+1); Xb dead (xf in regs)
                    const bf16* nx = xsrc + (size_t)(ks + 1) * 8192 + t * 8;
#pragma unroll
                    for (int r = 0; r < 4; r++)
                        gld_lds16(nx + r * 2048, &Xb[r * 2048 + t * 8]);
                }
                bf16x8 wf[2][2];
#pragma unroll
                for (int kk = 0; kk < 2; kk++)
#pragma unroll
                    for (int mt = 0; mt < 2; mt++)
                        wf[kk][mt] = *(const bf16x8*)
                            &Wb[1][((kk * 4 + wm * 2 + mt) * 64 + lane) * 8];
#pragma unroll
                for (int mt = 0; mt < 2; mt++)
#pragma unroll
                    for (int bt = 0; bt < 4; bt++) {
                        f32x4 p = __builtin_amdgcn_mfma_f32_16x16x32_bf16(
                            wf[0][mt], xf[bt][0], fz, 0, 0, 0);
                        p = __builtin_amdgcn_mfma_f32_16x16x32_bf16(
                            wf[1][mt], xf[bt][1], p, 0, 0, 0);
                        acc[mt][bt] += sc2[bt][1] * p;
                    }
                __syncthreads();           // Wb[0] staged; Wb[1] consumers done
            }
        }
    }

    // ---- bias as one MFMA k-step: A = bias^T frag, B = cw frag ----
    {
        bf16x8 bfrag[2];
#pragma unroll
        for (int mt = 0; mt < 2; mt++) {
            bf16x8 v;
#pragma unroll
            for (int j = 0; j < 8; j++) v[j] = (bf16)0.f;
            if (lq < 2) {                  // k = lq*8+j in 0..15 real
                int og = o0 + wm * 32 + mt * 16 + lr;
#pragma unroll
                for (int j = 0; j < 8; j++)
                    v[j] = (bf16)bias[(size_t)(lq * 8 + j) * OUT_DIM + og];
            }
            bfrag[mt] = v;
        }
#pragma unroll
        for (int bt = 0; bt < 4; bt++) {
            bf16x8 cf;
#pragma unroll
            for (int j = 0; j < 8; j++) cf[j] = (bf16)0.f;
            if (lq < 2) {
                const float* cr = cwl + bt * 16 * NEXP + lq * 8;
                f32x4 a = *(const f32x4*)cr;
                f32x4 b = *(const f32x4*)(cr + 4);
#pragma unroll
                for (int j = 0; j < 4; j++) { cf[j] = (bf16)a[j]; cf[4 + j] = (bf16)b[j]; }
            }
#pragma unroll
            for (int mt = 0; mt < 2; mt++)
                acc[mt][bt] = __builtin_amdgcn_mfma_f32_16x16x32_bf16(
                    bfrag[mt], cf, acc[mt][bt], 0, 0, 0);
        }
    }

    // epilogue: D[o,b] -> out[b,o]; lane f32x4 = 4 consecutive o at fixed b
#pragma unroll
    for (int mt = 0; mt < 2; mt++) {
        int og = o0 + wm * 32 + mt * 16 + lq * 4;
#pragma unroll
        for (int bt = 0; bt < 4; bt++) {
            int bg = b0 + wb * 64 + bt * 16 + lr;
            f32x4 v = acc[mt][bt];
#pragma unroll
            for (int r2 = 0; r2 < 4; r2++) v[r2] = v[r2] > 0.f ? v[r2] : 0.f;
            *(f32x4*)(out + (size_t)bg * OUT_DIM + og) = v;
        }
    }
}

// ---------------------------------------------------------------------------
// Insurance fallback if ws_size is too small.
// ---------------------------------------------------------------------------
__global__ void fallback_kernel(const float* __restrict__ x, const float* __restrict__ cw,
                                const float* __restrict__ W, const float* __restrict__ bias,
                                float* __restrict__ out) {
    int o = blockIdx.x * 256 + threadIdx.x;
    int b = o >> 10, oc = o & 1023;
    const float* xr = x + (size_t)b * IN_DIM;
    float accv = 0.f;
    for (int n = 0; n < NEXP; n++) {
        const float* wr = W + (size_t)n * IN_DIM * OUT_DIM + oc;
        float z = 0.f;
        for (int i = 0; i < IN_DIM; i++) z += xr[i] * wr[(size_t)i * OUT_DIM];
        accv += cw[(size_t)b * NEXP + n] * (z + bias[n * OUT_DIM + oc]);
    }
    out[o] = accv > 0.f ? accv : 0.f;
}

extern "C" void kernel_launch(void* const* d_in, const int* in_sizes, int n_in,
                              void* d_out, int out_size, void* d_ws, size_t ws_size,
                              hipStream_t stream) {
    const float* x    = (const float*)d_in[0];
    const float* cw   = (const float*)d_in[1];
    const float* W    = (const float*)d_in[2];
    const float* bias = (const float*)d_in[3];
    float* out = (float*)d_out;

    const size_t wt_elems = (size_t)NEXP * IN_DIM * OUT_DIM;   // 32 MB bf16
    const size_t xt_elems = (size_t)BATCH * IN_DIM;            // 8 MB bf16
    if (ws_size < (wt_elems + xt_elems) * sizeof(bf16)) {
        fallback_kernel<<<(BATCH * OUT_DIM) / 256, 256, 0, stream>>>(x, cw, W, bias, out);
        return;
    }
    bf16* wt2 = (bf16*)d_ws;
    bf16* xt = wt2 + wt_elems;

    pre_convert<<<2560, 256, 0, stream>>>(x, W, xt, wt2);
    moe_gemm_t3<<<dim3(32, 16), 256, 0, stream>>>(cw, bias, xt, wt2, out);
}